// Round 3
// baseline (227.020 us; speedup 1.0000x reference)
//
#include <hip/hip_runtime.h>

// NeRF compositing, round 2 (resubmit — broker timeout, never measured):
// one wave per ray *iteration*, 8 rays per wave with a 2-deep register
// pipeline (prefetch next ray's loads before processing the current ray).
// Cross-lane work minimized: 6-step shfl_up multiply-scan,
// quantity-interleaved 6-step butterfly reduce (instead of 24 shuffles),
// readlane for the no_hit broadcast.

#define SAMPLES 128
#define RAYS_PER_WAVE 8

struct RayData {
    float2 sg, dt, zv;      // sigma, dists, z_vals  (samples 2l, 2l+1)
    float2 c01, c23, c45;   // rgb: r0 g0 | b0 r1 | g1 b1
    float  bgv;             // bg channel `lane` for lane<3, else 0
};

__device__ __forceinline__ RayData load_ray(
    const float* __restrict__ sigma, const float* __restrict__ rgb,
    const float* __restrict__ dists, const float* __restrict__ zvals,
    const float* __restrict__ bg, int ray, int lane)
{
    RayData rd;
    const size_t base = (size_t)ray * SAMPLES;
    rd.sg = *reinterpret_cast<const float2*>(sigma + base + 2 * lane);
    rd.dt = *reinterpret_cast<const float2*>(dists + base + 2 * lane);
    rd.zv = *reinterpret_cast<const float2*>(zvals + base + 2 * lane);
    const float* rgbp = rgb + base * 3 + 6 * lane;
    rd.c01 = *reinterpret_cast<const float2*>(rgbp + 0);
    rd.c23 = *reinterpret_cast<const float2*>(rgbp + 2);
    rd.c45 = *reinterpret_cast<const float2*>(rgbp + 4);
    rd.bgv = (lane < 3) ? bg[(size_t)ray * 3 + lane] : 0.0f;
    return rd;
}

__device__ __forceinline__ void process_ray(
    const RayData& rd, int ray, int lane, float* __restrict__ out)
{
    const float eps = 1e-10f;
    const float tau0 = fmaxf(rd.sg.x, 0.0f) * rd.dt.x;
    const float tau1 = fmaxf(rd.sg.y, 0.0f) * rd.dt.y;
    const float a0 = 1.0f - __expf(-tau0);
    const float a1 = 1.0f - __expf(-tau1);
    const float f0 = 1.0f - a0 + eps;
    const float f1 = 1.0f - a1 + eps;

    // Inclusive multiply-scan across lanes of p = f0*f1.
    float scan = f0 * f1;
    #pragma unroll
    for (int off = 1; off < 64; off <<= 1) {
        const float up = __shfl_up(scan, off);
        scan *= (lane >= off) ? up : 1.0f;
    }
    float excl = __shfl_up(scan, 1);            // transmittance before sample 2l
    if (lane == 0) excl = 1.0f;
    // no_hit = product over all 128 factors = scan @ lane 63 (SGPR broadcast)
    const float no_hit =
        __uint_as_float(__builtin_amdgcn_readlane(__float_as_uint(scan), 63));

    const float w0 = a0 * excl;
    const float w1 = a1 * (excl * f0);

    float r = w0 * rd.c01.x + w1 * rd.c23.y;
    float g = w0 * rd.c01.y + w1 * rd.c45.x;
    float b = w0 * rd.c23.x + w1 * rd.c45.y;
    float d = w0 * rd.zv.x  + w1 * rd.zv.y;

    // Quantity-interleaved butterfly: after 2 steps lane (l%4) owns one of
    // {r,g,b,d}; 4 more xor steps complete the 64-lane sum. 6 DS ops total.
    // step1 (xor 1): lane even: X = r_l + r_{l^1}, Y = b_l + b_{l^1}
    //                lane odd : X = g_l + g_{l^1}, Y = d_l + d_{l^1}
    const bool o1 = lane & 1;
    const float X = (o1 ? g : r) + __shfl_xor(o1 ? r : g, 1);
    const float Y = (o1 ? d : b) + __shfl_xor(o1 ? b : d, 1);
    // step2 (xor 2): lane%4 == 0->r, 1->g, 2->b, 3->d  (verified lanes 0..3).
    const bool o2 = lane & 2;
    float Z = (o2 ? Y : X) + __shfl_xor(o2 ? X : Y, 2);
    #pragma unroll
    for (int off = 4; off < 64; off <<= 1) Z += __shfl_xor(Z, off);

    // lanes 0..2: color + no_hit*bg ; lane 3: depth (bgv==0 there).
    const float val = fmaf(no_hit, rd.bgv, Z);
    if (lane < 4) out[(size_t)ray * 4 + lane] = val;
}

__global__ __launch_bounds__(256, 8) void raymarch_composite(
    const float* __restrict__ sigma, const float* __restrict__ rgb,
    const float* __restrict__ dists, const float* __restrict__ zvals,
    const float* __restrict__ bg, float* __restrict__ out, int n_rays)
{
    const int lane  = threadIdx.x & 63;
    const int wave  = threadIdx.x >> 6;
    const int gwave = blockIdx.x * (blockDim.x >> 6) + wave;
    const int ray0  = gwave * RAYS_PER_WAVE;
    if (ray0 >= n_rays) return;

    RayData cur = load_ray(sigma, rgb, dists, zvals, bg, ray0, lane);
    #pragma unroll 1
    for (int i = 0; i < RAYS_PER_WAVE; ++i) {
        const int ray = ray0 + i;
        if (ray >= n_rays) break;
        RayData nxt;
        const int nray = ray + 1;
        if (i + 1 < RAYS_PER_WAVE && nray < n_rays)
            nxt = load_ray(sigma, rgb, dists, zvals, bg, nray, lane);
        process_ray(cur, ray, lane, out);
        cur = nxt;
    }
}

extern "C" void kernel_launch(void* const* d_in, const int* in_sizes, int n_in,
                              void* d_out, int out_size, void* d_ws, size_t ws_size,
                              hipStream_t stream) {
    const float* sigma = (const float*)d_in[0];
    const float* rgb   = (const float*)d_in[1];
    const float* dists = (const float*)d_in[2];
    const float* zvals = (const float*)d_in[3];
    const float* bg    = (const float*)d_in[4];
    float* out = (float*)d_out;

    const int n_rays = in_sizes[0] / SAMPLES;                 // 65536
    const int n_waves = (n_rays + RAYS_PER_WAVE - 1) / RAYS_PER_WAVE;  // 8192
    const int waves_per_block = 256 / 64;
    const int grid = (n_waves + waves_per_block - 1) / waves_per_block; // 2048

    raymarch_composite<<<grid, 256, 0, stream>>>(sigma, rgb, dists, zvals, bg,
                                                 out, n_rays);
}

// Round 6
// 217.022 us; speedup vs baseline: 1.0461x; 1.0461x over previous
//
#include <hip/hip_runtime.h>

// NeRF compositing, round 4 design (2nd resubmit — broker timeouts, never
// measured): 16 lanes per ray, 8 samples per lane. Per-lane serial cumprod +
// weighted sums (no cross-lane), then a 16-lane multiply-scan and 4-quantity
// reduction done ENTIRELY with DPP (VALU pipe, within-row ops — legal for
// 16-lane ray groups). Only one DS op per wave (shfl broadcast of no_hit).
// Rounds 1/3 showed DS-shuffle chains dominate this latency-bound kernel;
// this removes them.

#define SAMPLES 128
#define LANES_PER_RAY 16   // 4 rays per wave, 8 samples per lane

// DPP helper: out = dpp(src) with `oldv` kept where the source lane is
// invalid (bound_ctrl=0). ctrl: row_shr:N=0x110+N, row_ror:N=0x120+N,
// quad_perm=0x00..0xFF.
template <int CTRL>
__device__ __forceinline__ float fdpp(float oldv, float src) {
    return __uint_as_float((unsigned)__builtin_amdgcn_update_dpp(
        (int)__float_as_uint(oldv), (int)__float_as_uint(src),
        CTRL, 0xF, 0xF, false));
}

__global__ __launch_bounds__(256) void raymarch_composite(
    const float* __restrict__ sigma,   // [N, 128]
    const float* __restrict__ rgb,     // [N, 128, 3]
    const float* __restrict__ dists,   // [N, 128]
    const float* __restrict__ zvals,   // [N, 128]
    const float* __restrict__ bg,      // [N, 3]
    float* __restrict__ out,           // [N, 4]
    int n_rays)
{
    const int lane = threadIdx.x & 63;
    const int gw   = blockIdx.x * (blockDim.x >> 6) + (threadIdx.x >> 6);
    const int grp  = lane >> 4;        // ray group within wave (0..3)
    const int pos  = lane & 15;        // lane position within ray (0..15)
    const int ray  = gw * 4 + grp;
    if (ray >= n_rays) return;

    // ---- loads: 12 independent dwordx4 + bg, all issued up front ----
    const size_t sbase = (size_t)ray * SAMPLES + pos * 8;   // 8 samples/lane
    const float4* sp = reinterpret_cast<const float4*>(sigma + sbase);
    const float4* dp = reinterpret_cast<const float4*>(dists + sbase);
    const float4* zp = reinterpret_cast<const float4*>(zvals + sbase);
    const float4* cp = reinterpret_cast<const float4*>(
        rgb + (size_t)ray * (SAMPLES * 3) + pos * 24);      // 24 floats/lane

    const float4 s0 = sp[0], s1 = sp[1];
    const float4 d0 = dp[0], d1 = dp[1];
    const float4 z0 = zp[0], z1 = zp[1];
    const float4 c0 = cp[0], c1 = cp[1], c2 = cp[2];
    const float4 c3 = cp[3], c4 = cp[4], c5 = cp[5];
    const float bgv = (pos < 3) ? bg[(size_t)ray * 3 + pos] : 0.0f;

    const float s[8] = {s0.x, s0.y, s0.z, s0.w, s1.x, s1.y, s1.z, s1.w};
    const float d[8] = {d0.x, d0.y, d0.z, d0.w, d1.x, d1.y, d1.z, d1.w};
    const float z[8] = {z0.x, z0.y, z0.z, z0.w, z1.x, z1.y, z1.z, z1.w};
    const float c[24] = {c0.x, c0.y, c0.z, c0.w, c1.x, c1.y, c1.z, c1.w,
                         c2.x, c2.y, c2.z, c2.w, c3.x, c3.y, c3.z, c3.w,
                         c4.x, c4.y, c4.z, c4.w, c5.x, c5.y, c5.z, c5.w};

    // ---- per-lane serial compositing over 8 samples (no cross-lane) ----
    // f = 1 - alpha + eps = exp(-tau) + eps  (exact restructuring of ref)
    const float eps = 1e-10f;
    float t = 1.0f;                    // local transmittance within this lane
    float r = 0.f, g = 0.f, b = 0.f, dep = 0.f;
    #pragma unroll
    for (int i = 0; i < 8; ++i) {
        const float tau = fmaxf(s[i], 0.0f) * d[i];
        const float e   = __expf(-tau);
        const float a   = 1.0f - e;
        const float f   = e + eps;
        const float w   = a * t;       // alpha * local prefix transmittance
        r   = fmaf(w, c[3 * i + 0], r);
        g   = fmaf(w, c[3 * i + 1], g);
        b   = fmaf(w, c[3 * i + 2], b);
        dep = fmaf(w, z[i], dep);
        t *= f;
    }

    // ---- 16-lane inclusive multiply-scan of local products, via DPP ----
    float sc = t;
    sc *= fdpp<0x111>(1.0f, sc);   // row_shr:1
    sc *= fdpp<0x112>(1.0f, sc);   // row_shr:2
    sc *= fdpp<0x114>(1.0f, sc);   // row_shr:4
    sc *= fdpp<0x118>(1.0f, sc);   // row_shr:8  -> inclusive prefix product
    const float excl = fdpp<0x111>(1.0f, sc);   // exclusive prefix (pos0 -> 1)

    // no_hit = inclusive product at pos 15 of this group (one DS op/wave).
    const float no_hit = __shfl(sc, lane | 15);

    // Scale local sums by the group-exclusive transmittance prefix.
    r *= excl; g *= excl; b *= excl; dep *= excl;

    // ---- 4-quantity interleaved reduction over 16 lanes, via DPP ----
    // step 1 (xor1, quad_perm(1,0,3,2)=0xB1): even pos own r/b, odd own g/d
    const bool o1 = pos & 1;
    float X  = o1 ? g : r, Xo = o1 ? r : g;
    float Y  = o1 ? dep : b, Yo = o1 ? b : dep;
    X += fdpp<0xB1>(0.0f, Xo);
    Y += fdpp<0xB1>(0.0f, Yo);
    // step 2 (xor2, quad_perm(2,3,0,1)=0x4E): pos%4 -> 0:r 1:g 2:b 3:d
    const bool o2 = pos & 2;
    float Z  = o2 ? Y : X, Zo = o2 ? X : Y;
    Z += fdpp<0x4E>(0.0f, Zo);
    // steps 3-4: sum the 4 quads of the row (row_ror:4 then row_ror:8)
    Z += fdpp<0x124>(0.0f, Z);
    Z += fdpp<0x128>(0.0f, Z);

    // ---- epilogue: lanes pos 0..3 write r,g,b,depth (+ bg compositing) ----
    if (pos < 4) {
        out[(size_t)ray * 4 + pos] = fmaf(no_hit, bgv, Z);  // bgv==0 at pos3
    }
}

extern "C" void kernel_launch(void* const* d_in, const int* in_sizes, int n_in,
                              void* d_out, int out_size, void* d_ws, size_t ws_size,
                              hipStream_t stream) {
    const float* sigma = (const float*)d_in[0];
    const float* rgb   = (const float*)d_in[1];
    const float* dists = (const float*)d_in[2];
    const float* zvals = (const float*)d_in[3];
    const float* bg    = (const float*)d_in[4];
    float* out = (float*)d_out;

    const int n_rays = in_sizes[0] / SAMPLES;              // 65536
    const int rays_per_block = 16;                         // 4 waves x 4 rays
    const int grid = (n_rays + rays_per_block - 1) / rays_per_block;  // 4096

    raymarch_composite<<<grid, 256, 0, stream>>>(sigma, rgb, dists, zvals, bg,
                                                 out, n_rays);
}

// Round 10
// 216.296 us; speedup vs baseline: 1.0496x; 1.0034x over previous
//
#include <hip/hip_runtime.h>

// NeRF compositing, round 7 design (4th submit — broker timeouts, never
// measured): dense-coalesced global loads via per-wave LDS bounce + the
// HW-verified round-4 DPP compute (16 lanes/ray, 8 samples/lane).
//
// Theory: rounds 1/3/4 all converge at 73-85us with every pipe <25% busy.
// Common factor: strided 16B-per-lane loads costing ~2.3 cache-line REQUESTS
// per 64B line (sigma 32B stride -> 2 req/line; rgb 96B stride -> ~2.7).
// 6.3 TB/s / 2.3 = the observed ~2.75 TB/s delivered. This kernel issues only
// dense 1KB-per-wave load instructions (1 request/line), stages through a
// per-wave LDS region (NO block barrier; intra-wave lgkmcnt ordering), then
// computes exactly as round 4.

#define SAMPLES 128

// DPP helper: out = dpp(src), `oldv` kept where source lane invalid/masked.
template <int CTRL>
__device__ __forceinline__ float fdpp(float oldv, float src) {
    return __uint_as_float((unsigned)__builtin_amdgcn_update_dpp(
        (int)__float_as_uint(oldv), (int)__float_as_uint(src),
        CTRL, 0xF, 0xF, false));
}

// Per-wave LDS region, float4 granules:
//   phase A (s/d/z): granule  arr*132 + row*33 + G    (row 0..3, G 0..31, +1 pad)
//   phase B (rgb)  : granule  row*97 + G              (row 0..3, G 0..95, +1 pad)
// Region = 396 granules (phase B aliases phase A; max slot 394 < 396).
#define WAVE_GRANS 396

__global__ __launch_bounds__(256) void raymarch_composite(
    const float* __restrict__ sigma,   // [N, 128]
    const float* __restrict__ rgb,     // [N, 128, 3]
    const float* __restrict__ dists,   // [N, 128]
    const float* __restrict__ zvals,   // [N, 128]
    const float* __restrict__ bg,      // [N, 3]
    float* __restrict__ out,           // [N, 4]
    int n_rays)
{
    __shared__ float4 lds4[4 * WAVE_GRANS];   // 25344 B / block

    const int lane = threadIdx.x & 63;
    const int wave = threadIdx.x >> 6;
    const int gw   = blockIdx.x * 4 + wave;   // global wave id
    const int grp  = lane >> 4;               // ray within wave (0..3)
    const int pos  = lane & 15;               // lane within ray (0..15)
    const int ray0 = gw * 4;                  // wave's first ray
    const int ray  = ray0 + grp;
    if (ray0 >= n_rays) return;
    const int wb = wave * WAVE_GRANS;

    // ---- issue ALL dense global loads up front (each instr: 1KB contiguous) --
    const float4* sg = reinterpret_cast<const float4*>(sigma + (size_t)ray0 * SAMPLES);
    const float4* dg = reinterpret_cast<const float4*>(dists + (size_t)ray0 * SAMPLES);
    const float4* zg = reinterpret_cast<const float4*>(zvals + (size_t)ray0 * SAMPLES);
    const float4* cg = reinterpret_cast<const float4*>(rgb   + (size_t)ray0 * SAMPLES * 3);

    const float4 sv0 = sg[lane],       sv1 = sg[lane + 64];
    const float4 dv0 = dg[lane],       dv1 = dg[lane + 64];
    const float4 zv0 = zg[lane],       zv1 = zg[lane + 64];
    const float4 cv0 = cg[lane],       cv1 = cg[lane + 64],  cv2 = cg[lane + 128];
    const float4 cv3 = cg[lane + 192], cv4 = cg[lane + 256], cv5 = cg[lane + 320];
    const float bgv = (pos < 3) ? bg[(size_t)ray * 3 + pos] : 0.0f;

    // ---- phase A: stage sigma/dists/zvals, re-read strided per lane ----
    // write: granule g = 64k + lane; row = g>>5; G = g&31; slot = arr*132+row*33+G
    {
        const int r0 = lane >> 5,        G0 = lane & 31;
        const int r1 = (lane + 64) >> 5, G1 = lane & 31;   // g1 = lane+64
        const int w0 = wb + r0 * 33 + G0, w1 = wb + r1 * 33 + G1;
        lds4[w0 +   0] = sv0;  lds4[w1 +   0] = sv1;
        lds4[w0 + 132] = dv0;  lds4[w1 + 132] = dv1;
        lds4[w0 + 264] = zv0;  lds4[w1 + 264] = zv1;
    }
    asm volatile("s_waitcnt lgkmcnt(0)" ::: "memory");  // writes visible wave-wide

    // read: lane owns samples 8*pos..8*pos+7 of ray grp -> granules 2p, 2p+1
    const int abase = wb + grp * 33 + 2 * pos;
    const float4 s01 = lds4[abase +   0], s23 = lds4[abase +   0 + 1];
    const float4 d01 = lds4[abase + 132], d23 = lds4[abase + 132 + 1];
    const float4 z01 = lds4[abase + 264], z23 = lds4[abase + 264 + 1];
    asm volatile("s_waitcnt lgkmcnt(0)" ::: "memory");  // reads retired before B writes

    // ---- phase B: stage rgb (aliases phase-A region), re-read strided ----
    // g = 64k + lane; row = g/96; G = g%96; slot = row*97 + G  (k-static splits)
    lds4[wb + lane] = cv0;
    lds4[wb + ((lane < 32) ? lane + 64 : lane + 65)] = cv1;
    lds4[wb + lane + 129] = cv2;
    lds4[wb + lane + 194] = cv3;
    lds4[wb + ((lane < 32) ? lane + 258 : lane + 259)] = cv4;
    lds4[wb + lane + 323] = cv5;
    asm volatile("s_waitcnt lgkmcnt(0)" ::: "memory");

    // read: lane needs rgb floats 24p..24p+23 of ray grp -> granules 6p..6p+5
    const int cbase = wb + grp * 97 + 6 * pos;
    const float4 c0 = lds4[cbase + 0], c1 = lds4[cbase + 1], c2 = lds4[cbase + 2];
    const float4 c3 = lds4[cbase + 3], c4 = lds4[cbase + 4], c5 = lds4[cbase + 5];

    const float s[8] = {s01.x, s01.y, s01.z, s01.w, s23.x, s23.y, s23.z, s23.w};
    const float d[8] = {d01.x, d01.y, d01.z, d01.w, d23.x, d23.y, d23.z, d23.w};
    const float z[8] = {z01.x, z01.y, z01.z, z01.w, z23.x, z23.y, z23.z, z23.w};
    const float c[24] = {c0.x, c0.y, c0.z, c0.w, c1.x, c1.y, c1.z, c1.w,
                         c2.x, c2.y, c2.z, c2.w, c3.x, c3.y, c3.z, c3.w,
                         c4.x, c4.y, c4.z, c4.w, c5.x, c5.y, c5.z, c5.w};

    // ---- per-lane serial compositing over 8 samples (round-4, HW-verified) --
    const float eps = 1e-10f;
    float t = 1.0f;
    float r = 0.f, g = 0.f, b = 0.f, dep = 0.f;
    #pragma unroll
    for (int i = 0; i < 8; ++i) {
        const float tau = fmaxf(s[i], 0.0f) * d[i];
        const float e   = __expf(-tau);
        const float a   = 1.0f - e;
        const float f   = e + eps;
        const float w   = a * t;
        r   = fmaf(w, c[3 * i + 0], r);
        g   = fmaf(w, c[3 * i + 1], g);
        b   = fmaf(w, c[3 * i + 2], b);
        dep = fmaf(w, z[i], dep);
        t *= f;
    }

    // ---- 16-lane inclusive multiply-scan via DPP ----
    float sc = t;
    sc *= fdpp<0x111>(1.0f, sc);   // row_shr:1
    sc *= fdpp<0x112>(1.0f, sc);   // row_shr:2
    sc *= fdpp<0x114>(1.0f, sc);   // row_shr:4
    sc *= fdpp<0x118>(1.0f, sc);   // row_shr:8
    const float excl = fdpp<0x111>(1.0f, sc);   // exclusive prefix (pos0 -> 1)

    const float no_hit = __shfl(sc, lane | 15); // group total (one DS op)

    r *= excl; g *= excl; b *= excl; dep *= excl;

    // ---- 4-quantity interleaved 16-lane reduction via DPP ----
    const bool o1 = pos & 1;
    float X = (o1 ? g : r) + fdpp<0xB1>(0.0f, o1 ? r : g);   // quad_perm xor1
    float Y = (o1 ? dep : b) + fdpp<0xB1>(0.0f, o1 ? b : dep);
    const bool o2 = pos & 2;
    float Z = (o2 ? Y : X) + fdpp<0x4E>(0.0f, o2 ? X : Y);   // quad_perm xor2
    Z += fdpp<0x124>(0.0f, Z);     // row_ror:4
    Z += fdpp<0x128>(0.0f, Z);     // row_ror:8

    // ---- epilogue: pos 0..2 -> rgb (+bg), pos 3 -> depth (bgv==0 there) ----
    if (pos < 4) {
        out[(size_t)ray * 4 + pos] = fmaf(no_hit, bgv, Z);
    }
}

extern "C" void kernel_launch(void* const* d_in, const int* in_sizes, int n_in,
                              void* d_out, int out_size, void* d_ws, size_t ws_size,
                              hipStream_t stream) {
    const float* sigma = (const float*)d_in[0];
    const float* rgb   = (const float*)d_in[1];
    const float* dists = (const float*)d_in[2];
    const float* zvals = (const float*)d_in[3];
    const float* bg    = (const float*)d_in[4];
    float* out = (float*)d_out;

    const int n_rays = in_sizes[0] / SAMPLES;              // 65536
    const int rays_per_block = 16;                         // 4 waves x 4 rays
    const int grid = (n_rays + rays_per_block - 1) / rays_per_block;  // 4096

    raymarch_composite<<<grid, 256, 0, stream>>>(sigma, rgb, dists, zvals, bg,
                                                 out, n_rays);
}